// Round 1
// baseline (213.500 us; speedup 1.0000x reference)
//
#include <hip/hip_runtime.h>
#include <cstdint>

// HSTU fused block on MI355X. Pipeline:
//   k0: convert x,W1,W2 fp32->bf16
//   k1: h = silu(x@W1^T+b1)  -> gate/q/k into h[8192][2048] (bf16), v -> Vt[b,h,d,t] transposed
//   k2: causal silu-attention (no softmax state): o[b,s,h*64+d] fp32
//   k3: y = layernorm(o)*g+b * gate  (bf16)
//   k4: out = y@W2^T + b2 (fp32)
// ws layout (bytes):
//   xb @0 (8MB) | w1b @8388608 (2MB) | w2b @10485760 (0.5MB) | h @11010048 (32MB)
//   vt @44564480 (8MB) | o @52953088 (16MB) | y @69730304 (8MB)  total ~74.5MB

typedef __attribute__((ext_vector_type(8))) short short8;
typedef __attribute__((ext_vector_type(4))) float f32x4;

__device__ __forceinline__ unsigned short f2bf(float f) {
  union { float f; unsigned u; } v; v.f = f;
  unsigned r = v.u + 0x7FFFu + ((v.u >> 16) & 1u);
  return (unsigned short)(r >> 16);
}
__device__ __forceinline__ float bf2f(unsigned short h) {
  union { unsigned u; float f; } v; v.u = ((unsigned)h) << 16; return v.f;
}
__device__ __forceinline__ float silu_f(float x) {
  return x / (1.0f + __expf(-x));
}
__device__ __forceinline__ void gl_lds16(const void* g, void* l) {
  // async global->LDS, 16B/lane, LDS dst = wave-uniform base + lane*16
  __builtin_amdgcn_global_load_lds(
      (const __attribute__((address_space(1))) void*)g,
      (__attribute__((address_space(3))) void*)l, 16, 0, 0);
}

// ---------------- k0: fp32 -> bf16 convert (x, W1, W2) ----------------
__global__ void convert_kernel(const float* __restrict__ x, const float* __restrict__ w1,
                               const float* __restrict__ w2,
                               unsigned short* __restrict__ xb, unsigned short* __restrict__ w1b,
                               unsigned short* __restrict__ w2b) {
  int i = blockIdx.x * 256 + threadIdx.x;  // one float4 per thread
  const float* s; unsigned short* d;
  if (i < 1048576) { s = x; d = xb; }
  else if (i < 1048576 + 262144) { i -= 1048576; s = w1; d = w1b; }
  else { i -= (1048576 + 262144); if (i >= 65536) return; s = w2; d = w2b; }
  float4 f = ((const float4*)s)[i];
  ushort4 o; o.x = f2bf(f.x); o.y = f2bf(f.y); o.z = f2bf(f.z); o.w = f2bf(f.w);
  ((ushort4*)d)[i] = o;
}

// ---------------- k1: GEMM1 + bias + silu, scatter gate/q/k -> h, v -> vt ----------------
__global__ __launch_bounds__(256, 2) void gemm1_kernel(
    const unsigned short* __restrict__ xb,   // [8192][512]
    const unsigned short* __restrict__ w1b,  // [2048][512]
    const float* __restrict__ b1,            // [2048]
    unsigned short* __restrict__ h,          // [8192][2048] (v quarter unused)
    unsigned short* __restrict__ vt)         // [32][64][2048]  (b*8+h, d, s)
{
  __shared__ __align__(16) unsigned short As[128 * 64];
  __shared__ __align__(16) unsigned short Bs[128 * 64];
  const int tid = threadIdx.x;
  const int w = tid >> 6, l = tid & 63;
  const int bm = blockIdx.x & 63, bn = blockIdx.x >> 6;
  const int wm = w & 1, wn = w >> 1;
  const int quad = l >> 4, lc = l & 15;
  const int r8 = l >> 3, c8 = l & 7;

  f32x4 acc[4][4] = {};

  const unsigned short* ga = xb + (bm * 128 + w * 32 + r8) * 512 + c8 * 8;
  const unsigned short* gb = w1b + (bn * 128 + w * 32 + r8) * 512 + c8 * 8;
  unsigned short* la = As + (w * 32) * 64;
  unsigned short* lb = Bs + (w * 32) * 64;

  for (int kt = 0; kt < 512; kt += 64) {
#pragma unroll
    for (int i = 0; i < 4; ++i) {
      gl_lds16(ga + i * 8 * 512 + kt, la + i * 8 * 64);
      gl_lds16(gb + i * 8 * 512 + kt, lb + i * 8 * 64);
    }
    __syncthreads();
#pragma unroll
    for (int kk = 0; kk < 2; ++kk) {
      short8 af[4], bf[4];
      const int ko = kk * 32 + quad * 8;
#pragma unroll
      for (int mt = 0; mt < 4; ++mt)
        af[mt] = *(const short8*)(As + (wm * 64 + mt * 16 + lc) * 64 + ko);
#pragma unroll
      for (int nt = 0; nt < 4; ++nt)
        bf[nt] = *(const short8*)(Bs + (wn * 64 + nt * 16 + lc) * 64 + ko);
#pragma unroll
      for (int mt = 0; mt < 4; ++mt)
#pragma unroll
        for (int nt = 0; nt < 4; ++nt)
          acc[mt][nt] = __builtin_amdgcn_mfma_f32_16x16x32_bf16(af[mt], bf[nt], acc[mt][nt], 0, 0, 0);
    }
    __syncthreads();
  }

  const int sec = bn >> 2;  // 0 gate, 1 q, 2 k, 3 v  (uniform per block)
  if (sec == 3) {
#pragma unroll
    for (int nt = 0; nt < 4; ++nt) {
      const int n = bn * 128 + wn * 64 + nt * 16 + lc;
      const float bias = b1[n];
      const int hh = (n >> 6) & 7, d = n & 63;
#pragma unroll
      for (int mt = 0; mt < 4; ++mt) {
        const int m0 = bm * 128 + wm * 64 + mt * 16 + quad * 4;
        const int b = m0 >> 11, s = m0 & 2047;
        ushort4 pk;
        pk.x = f2bf(silu_f(acc[mt][nt][0] + bias));
        pk.y = f2bf(silu_f(acc[mt][nt][1] + bias));
        pk.z = f2bf(silu_f(acc[mt][nt][2] + bias));
        pk.w = f2bf(silu_f(acc[mt][nt][3] + bias));
        *(ushort4*)(vt + ((b * 8 + hh) * 64 + d) * 2048 + s) = pk;
      }
    }
  } else {
#pragma unroll
    for (int nt = 0; nt < 4; ++nt) {
      const int n = bn * 128 + wn * 64 + nt * 16 + lc;
      const float bias = b1[n];
#pragma unroll
      for (int mt = 0; mt < 4; ++mt) {
        const int m0 = bm * 128 + wm * 64 + mt * 16 + quad * 4;
#pragma unroll
        for (int r = 0; r < 4; ++r)
          h[(m0 + r) * 2048 + n] = f2bf(silu_f(acc[mt][nt][r] + bias));
      }
    }
  }
}

// ---------------- k2: causal silu-attention ----------------
__global__ __launch_bounds__(256, 2) void attn_kernel(
    const unsigned short* __restrict__ h,   // q @ +512, k @ +1024
    const unsigned short* __restrict__ vt,  // [32][64][2048]
    float* __restrict__ o)                  // [8192][512] = [b][s][hh*64+d]
{
  __shared__ __align__(16) unsigned short Ks[128 * 64];   // [t][d]
  __shared__ __align__(16) unsigned short Vs[64 * 128];   // [d][t]
  __shared__ __align__(16) unsigned short Ps[128 * 136];  // [q][t] pad+8 ; also Q staging area
  const int tid = threadIdx.x;
  const int w = tid >> 6, l = tid & 63;
  const int bh = blockIdx.x & 31;
  const int qi = 15 - (blockIdx.x >> 5);   // big tiles first
  const int b = bh >> 3, hh = bh & 7;
  const int wm = w & 1, wn = w >> 1;
  const int quad = l >> 4, lc = l & 15;
  const int r8 = l >> 3, c8 = l & 7;

  // stage Q tile [128][64] into Ps area
  {
    const unsigned short* qg = h + (b * 2048 + qi * 128 + w * 32 + r8) * 2048 + 512 + hh * 64 + c8 * 8;
    unsigned short* qs = Ps + (w * 32) * 64;
#pragma unroll
    for (int i = 0; i < 4; ++i)
      gl_lds16(qg + i * 8 * 2048, qs + i * 8 * 64);
  }
  __syncthreads();
  short8 qf[4][2];
#pragma unroll
  for (int mt = 0; mt < 4; ++mt)
#pragma unroll
    for (int kk = 0; kk < 2; ++kk)
      qf[mt][kk] = *(const short8*)(Ps + (wm * 64 + mt * 16 + lc) * 64 + kk * 32 + quad * 8);

  f32x4 oacc[2][4] = {};

  const unsigned short* kg = h + (b * 2048 + w * 32 + r8) * 2048 + 1024 + hh * 64 + c8 * 8;
  const unsigned short* vg = vt + (bh * 64 + w * 16 + quad) * 2048 + lc * 8;

  for (int ti = 0; ti <= qi; ++ti) {
    __syncthreads();  // previous iteration's LDS readers done
    const int toff = ti * 128;
#pragma unroll
    for (int i = 0; i < 4; ++i) {
      gl_lds16(kg + (toff + i * 8) * 2048, Ks + (w * 32 + i * 8) * 64);
      gl_lds16(vg + toff + i * 4 * 2048, Vs + (w * 16 + i * 4) * 128);
    }
    __syncthreads();

    // Sc = Q K^T : wave covers q[wm*64..+64) x t[wn*64..+64)
    f32x4 sc[4][4] = {};
#pragma unroll
    for (int kk = 0; kk < 2; ++kk) {
      short8 kf[4];
      const int ko = kk * 32 + quad * 8;
#pragma unroll
      for (int nt = 0; nt < 4; ++nt)
        kf[nt] = *(const short8*)(Ks + (wn * 64 + nt * 16 + lc) * 64 + ko);
#pragma unroll
      for (int mt = 0; mt < 4; ++mt)
#pragma unroll
        for (int nt = 0; nt < 4; ++nt)
          sc[mt][nt] = __builtin_amdgcn_mfma_f32_16x16x32_bf16(qf[mt][kk], kf[nt], sc[mt][nt], 0, 0, 0);
    }

    // scale + silu (+ causal mask only on diagonal tile) -> Ps (bf16)
    if (ti < qi) {
#pragma unroll
      for (int mt = 0; mt < 4; ++mt) {
        const int qr = wm * 64 + mt * 16 + quad * 4;
#pragma unroll
        for (int nt = 0; nt < 4; ++nt) {
          const int tc = wn * 64 + nt * 16 + lc;
#pragma unroll
          for (int r = 0; r < 4; ++r)
            Ps[(qr + r) * 136 + tc] = f2bf(silu_f(sc[mt][nt][r] * 0.125f));
        }
      }
    } else {
#pragma unroll
      for (int mt = 0; mt < 4; ++mt) {
        const int qr = wm * 64 + mt * 16 + quad * 4;
#pragma unroll
        for (int nt = 0; nt < 4; ++nt) {
          const int tc = wn * 64 + nt * 16 + lc;
#pragma unroll
          for (int r = 0; r < 4; ++r) {
            unsigned short pb = (tc <= qr + r) ? f2bf(silu_f(sc[mt][nt][r] * 0.125f))
                                               : (unsigned short)0;
            Ps[(qr + r) * 136 + tc] = pb;
          }
        }
      }
    }
    __syncthreads();

    // O += P V : wave covers q[w*32..+32) x d[0..64)
#pragma unroll
    for (int ks = 0; ks < 4; ++ks) {
      short8 pf[2], vf[4];
      const int ko = ks * 32 + quad * 8;
#pragma unroll
      for (int mt = 0; mt < 2; ++mt)
        pf[mt] = *(const short8*)(Ps + (w * 32 + mt * 16 + lc) * 136 + ko);
#pragma unroll
      for (int nt = 0; nt < 4; ++nt)
        vf[nt] = *(const short8*)(Vs + (nt * 16 + lc) * 128 + ko);
#pragma unroll
      for (int mt = 0; mt < 2; ++mt)
#pragma unroll
        for (int nt = 0; nt < 4; ++nt)
          oacc[mt][nt] = __builtin_amdgcn_mfma_f32_16x16x32_bf16(pf[mt], vf[nt], oacc[mt][nt], 0, 0, 0);
    }
  }

  float* og = o + (b * 2048 + qi * 128 + w * 32) * 512 + hh * 64;
#pragma unroll
  for (int mt = 0; mt < 2; ++mt)
#pragma unroll
    for (int nt = 0; nt < 4; ++nt)
#pragma unroll
      for (int r = 0; r < 4; ++r)
        og[(mt * 16 + quad * 4 + r) * 512 + nt * 16 + lc] = oacc[mt][nt][r];
}

// ---------------- k3: layernorm * gate -> y (bf16) ----------------
__global__ __launch_bounds__(256) void ln_gate_kernel(
    const float* __restrict__ o, const unsigned short* __restrict__ h,
    const float* __restrict__ lng, const float* __restrict__ lnb,
    unsigned short* __restrict__ y) {
  const int row = blockIdx.x * 4 + (threadIdx.x >> 6);
  const int l = threadIdx.x & 63;
  const float4* orow = (const float4*)(o + row * 512);
  float4 a = orow[l * 2], c = orow[l * 2 + 1];
  float s0 = a.x + a.y + a.z + a.w + c.x + c.y + c.z + c.w;
#pragma unroll
  for (int off = 32; off > 0; off >>= 1) s0 += __shfl_xor(s0, off);
  const float mean = s0 * (1.0f / 512.0f);
  float dx[8] = {a.x - mean, a.y - mean, a.z - mean, a.w - mean,
                 c.x - mean, c.y - mean, c.z - mean, c.w - mean};
  float sq = 0.f;
#pragma unroll
  for (int j = 0; j < 8; ++j) sq += dx[j] * dx[j];
#pragma unroll
  for (int off = 32; off > 0; off >>= 1) sq += __shfl_xor(sq, off);
  const float inv = rsqrtf(sq * (1.0f / 512.0f) + 1e-5f);
  const float4* g4 = (const float4*)lng;
  const float4* b4 = (const float4*)lnb;
  float4 g0 = g4[l * 2], g1 = g4[l * 2 + 1], bb0 = b4[l * 2], bb1 = b4[l * 2 + 1];
  const unsigned short* grow = h + row * 2048;  // gate section = cols [0,512)
  ushort4 gr0 = *(const ushort4*)(grow + l * 8);
  ushort4 gr1 = *(const ushort4*)(grow + l * 8 + 4);
  float gg[8] = {g0.x, g0.y, g0.z, g0.w, g1.x, g1.y, g1.z, g1.w};
  float bbv[8] = {bb0.x, bb0.y, bb0.z, bb0.w, bb1.x, bb1.y, bb1.z, bb1.w};
  float gv[8] = {bf2f(gr0.x), bf2f(gr0.y), bf2f(gr0.z), bf2f(gr0.w),
                 bf2f(gr1.x), bf2f(gr1.y), bf2f(gr1.z), bf2f(gr1.w)};
  ushort4 p0, p1;
  p0.x = f2bf((dx[0] * inv * gg[0] + bbv[0]) * gv[0]);
  p0.y = f2bf((dx[1] * inv * gg[1] + bbv[1]) * gv[1]);
  p0.z = f2bf((dx[2] * inv * gg[2] + bbv[2]) * gv[2]);
  p0.w = f2bf((dx[3] * inv * gg[3] + bbv[3]) * gv[3]);
  p1.x = f2bf((dx[4] * inv * gg[4] + bbv[4]) * gv[4]);
  p1.y = f2bf((dx[5] * inv * gg[5] + bbv[5]) * gv[5]);
  p1.z = f2bf((dx[6] * inv * gg[6] + bbv[6]) * gv[6]);
  p1.w = f2bf((dx[7] * inv * gg[7] + bbv[7]) * gv[7]);
  ushort4* yrow = (ushort4*)(y + row * 512);
  yrow[l * 2] = p0;
  yrow[l * 2 + 1] = p1;
}

// ---------------- k4: GEMM2 + bias -> out (fp32) ----------------
__global__ __launch_bounds__(256, 2) void gemm2_kernel(
    const unsigned short* __restrict__ yb,   // [8192][512]
    const unsigned short* __restrict__ w2b,  // [512][512]
    const float* __restrict__ b2, float* __restrict__ out) {
  __shared__ __align__(16) unsigned short As[128 * 64];
  __shared__ __align__(16) unsigned short Bs[128 * 64];
  const int tid = threadIdx.x;
  const int w = tid >> 6, l = tid & 63;
  const int bm = blockIdx.x & 63, bn = blockIdx.x >> 6;
  const int wm = w & 1, wn = w >> 1;
  const int quad = l >> 4, lc = l & 15;
  const int r8 = l >> 3, c8 = l & 7;

  f32x4 acc[4][4] = {};
  const unsigned short* ga = yb + (bm * 128 + w * 32 + r8) * 512 + c8 * 8;
  const unsigned short* gb = w2b + (bn * 128 + w * 32 + r8) * 512 + c8 * 8;
  unsigned short* la = As + (w * 32) * 64;
  unsigned short* lb = Bs + (w * 32) * 64;

  for (int kt = 0; kt < 512; kt += 64) {
#pragma unroll
    for (int i = 0; i < 4; ++i) {
      gl_lds16(ga + i * 8 * 512 + kt, la + i * 8 * 64);
      gl_lds16(gb + i * 8 * 512 + kt, lb + i * 8 * 64);
    }
    __syncthreads();
#pragma unroll
    for (int kk = 0; kk < 2; ++kk) {
      short8 af[4], bf[4];
      const int ko = kk * 32 + quad * 8;
#pragma unroll
      for (int mt = 0; mt < 4; ++mt)
        af[mt] = *(const short8*)(As + (wm * 64 + mt * 16 + lc) * 64 + ko);
#pragma unroll
      for (int nt = 0; nt < 4; ++nt)
        bf[nt] = *(const short8*)(Bs + (wn * 64 + nt * 16 + lc) * 64 + ko);
#pragma unroll
      for (int mt = 0; mt < 4; ++mt)
#pragma unroll
        for (int nt = 0; nt < 4; ++nt)
          acc[mt][nt] = __builtin_amdgcn_mfma_f32_16x16x32_bf16(af[mt], bf[nt], acc[mt][nt], 0, 0, 0);
    }
    __syncthreads();
  }

#pragma unroll
  for (int nt = 0; nt < 4; ++nt) {
    const int n = bn * 128 + wn * 64 + nt * 16 + lc;
    const float bias = b2[n];
#pragma unroll
    for (int mt = 0; mt < 4; ++mt) {
      const int m0 = bm * 128 + wm * 64 + mt * 16 + quad * 4;
#pragma unroll
      for (int r = 0; r < 4; ++r)
        out[(m0 + r) * 512 + n] = acc[mt][nt][r] + bias;
    }
  }
}

extern "C" void kernel_launch(void* const* d_in, const int* in_sizes, int n_in,
                              void* d_out, int out_size, void* d_ws, size_t ws_size,
                              hipStream_t stream) {
  const float* x = (const float*)d_in[0];
  const float* W1 = (const float*)d_in[1];
  const float* b1 = (const float*)d_in[2];
  const float* lng = (const float*)d_in[3];
  const float* lnb = (const float*)d_in[4];
  const float* W2 = (const float*)d_in[5];
  const float* b2 = (const float*)d_in[6];
  float* out = (float*)d_out;
  char* ws = (char*)d_ws;

  unsigned short* xb  = (unsigned short*)(ws);
  unsigned short* w1b = (unsigned short*)(ws + 8388608);
  unsigned short* w2b = (unsigned short*)(ws + 10485760);
  unsigned short* h   = (unsigned short*)(ws + 11010048);
  unsigned short* vt  = (unsigned short*)(ws + 44564480);
  float* o            = (float*)(ws + 52953088);
  unsigned short* yb  = (unsigned short*)(ws + 69730304);

  convert_kernel<<<5376, 256, 0, stream>>>(x, W1, W2, xb, w1b, w2b);
  gemm1_kernel<<<1024, 256, 0, stream>>>(xb, w1b, b1, h, vt);
  attn_kernel<<<512, 256, 0, stream>>>(h, vt, o);
  ln_gate_kernel<<<2048, 256, 0, stream>>>(o, h, lng, lnb, yb);
  gemm2_kernel<<<256, 256, 0, stream>>>(yb, w2b, b2, out);
}

// Round 2
// 182.452 us; speedup vs baseline: 1.1702x; 1.1702x over previous
//
#include <hip/hip_runtime.h>
#include <cstdint>

// HSTU fused block on MI355X. Pipeline:
//   k0: convert x,W1,W2 fp32->bf16
//   k1: h = silu(x@W1^T+b1) -> gate/q/k into h[8192][2048] (q pre-scaled by 0.125), v -> Vt[b,h,d,t]
//   k2: causal silu-attention: o[b,s,h*64+d] fp32   (Q-tile 64, K-tile 128, LPT dispatch)
//   k3: y = (layernorm(o)*g+b) * gate  (bf16)
//   k4: out = y@W2^T + b2 (fp32)
// ws layout (bytes):
//   xb @0 (8MB) | w1b @8388608 (2MB) | w2b @10485760 (0.5MB) | h @11010048 (32MB)
//   vt @44564480 (8MB) | o @52953088 (16MB) | y @69730304 (8MB)  total ~74.5MB

typedef __attribute__((ext_vector_type(8))) short short8;
typedef __attribute__((ext_vector_type(4))) float f32x4;

__device__ __forceinline__ unsigned short f2bf(float f) {
  union { float f; unsigned u; } v; v.f = f;
  unsigned r = v.u + 0x7FFFu + ((v.u >> 16) & 1u);
  return (unsigned short)(r >> 16);
}
__device__ __forceinline__ float bf2f(unsigned short h) {
  union { unsigned u; float f; } v; v.u = ((unsigned)h) << 16; return v.f;
}
__device__ __forceinline__ float silu_f(float x) {
  return x / (1.0f + __expf(-x));
}
__device__ __forceinline__ void gl_lds16(const void* g, void* l) {
  // async global->LDS, 16B/lane; global addr is per-lane, LDS dst = uniform base + lane*16
  __builtin_amdgcn_global_load_lds(
      (const __attribute__((address_space(1))) void*)g,
      (__attribute__((address_space(3))) void*)l, 16, 0, 0);
}

// ---------------- k0: fp32 -> bf16 convert (x, W1, W2) ----------------
__global__ void convert_kernel(const float* __restrict__ x, const float* __restrict__ w1,
                               const float* __restrict__ w2,
                               unsigned short* __restrict__ xb, unsigned short* __restrict__ w1b,
                               unsigned short* __restrict__ w2b) {
  int i = blockIdx.x * 256 + threadIdx.x;  // one float4 per thread
  const float* s; unsigned short* d;
  if (i < 1048576) { s = x; d = xb; }
  else if (i < 1048576 + 262144) { i -= 1048576; s = w1; d = w1b; }
  else { i -= (1048576 + 262144); if (i >= 65536) return; s = w2; d = w2b; }
  float4 f = ((const float4*)s)[i];
  ushort4 o; o.x = f2bf(f.x); o.y = f2bf(f.y); o.z = f2bf(f.z); o.w = f2bf(f.w);
  ((ushort4*)d)[i] = o;
}

// ---------------- k1: GEMM1 + bias + silu, scatter gate/q/k -> h, v -> vt ----------------
// LDS tiles grouped: [16 groups][8 rows][64], group stride 528 shorts (16B pad per 1KB granule)
__global__ __launch_bounds__(256, 2) void gemm1_kernel(
    const unsigned short* __restrict__ xb,   // [8192][512]
    const unsigned short* __restrict__ w1b,  // [2048][512]
    const float* __restrict__ b1,            // [2048]
    unsigned short* __restrict__ h,          // [8192][2048] (v quarter unused)
    unsigned short* __restrict__ vt)         // [32][64][2048]  (b*8+h, d, s)
{
  __shared__ __align__(16) unsigned short As[16 * 528];
  __shared__ __align__(16) unsigned short Bs[16 * 528];
  const int tid = threadIdx.x;
  const int w = tid >> 6, l = tid & 63;
  const int bm = blockIdx.x & 63, bn = blockIdx.x >> 6;
  const int wm = w & 1, wn = w >> 1;
  const int quad = l >> 4, lc = l & 15;
  const int r8 = l >> 3, c8 = l & 7;
  const int lanebase = (lc >> 3) * 528 + (lc & 7) * 64 + quad * 8;

  f32x4 acc[4][4] = {};

  const unsigned short* ga = xb + (size_t)(bm * 128 + w * 32 + r8) * 512 + c8 * 8;
  const unsigned short* gb = w1b + (size_t)(bn * 128 + w * 32 + r8) * 512 + c8 * 8;

  for (int kt = 0; kt < 512; kt += 64) {
#pragma unroll
    for (int i = 0; i < 4; ++i) {
      gl_lds16(ga + i * 8 * 512 + kt, As + (w * 4 + i) * 528);
      gl_lds16(gb + i * 8 * 512 + kt, Bs + (w * 4 + i) * 528);
    }
    __syncthreads();
#pragma unroll
    for (int kk = 0; kk < 2; ++kk) {
      short8 af[4], bf[4];
#pragma unroll
      for (int mt = 0; mt < 4; ++mt)
        af[mt] = *(const short8*)(As + (wm * 8 + mt * 2) * 528 + lanebase + kk * 32);
#pragma unroll
      for (int nt = 0; nt < 4; ++nt)
        bf[nt] = *(const short8*)(Bs + (wn * 8 + nt * 2) * 528 + lanebase + kk * 32);
#pragma unroll
      for (int mt = 0; mt < 4; ++mt)
#pragma unroll
        for (int nt = 0; nt < 4; ++nt)
          acc[mt][nt] = __builtin_amdgcn_mfma_f32_16x16x32_bf16(af[mt], bf[nt], acc[mt][nt], 0, 0, 0);
    }
    __syncthreads();
  }

  const int sec = bn >> 2;  // 0 gate, 1 q, 2 k, 3 v  (uniform per block)
  if (sec == 3) {
#pragma unroll
    for (int nt = 0; nt < 4; ++nt) {
      const int n = bn * 128 + wn * 64 + nt * 16 + lc;
      const float bias = b1[n];
      const int hh = (n >> 6) & 7, d = n & 63;
#pragma unroll
      for (int mt = 0; mt < 4; ++mt) {
        const int m0 = bm * 128 + wm * 64 + mt * 16 + quad * 4;
        const int b = m0 >> 11, s = m0 & 2047;
        ushort4 pk;
        pk.x = f2bf(silu_f(acc[mt][nt][0] + bias));
        pk.y = f2bf(silu_f(acc[mt][nt][1] + bias));
        pk.z = f2bf(silu_f(acc[mt][nt][2] + bias));
        pk.w = f2bf(silu_f(acc[mt][nt][3] + bias));
        *(ushort4*)(vt + (size_t)((b * 8 + hh) * 64 + d) * 2048 + s) = pk;
      }
    }
  } else {
    const float osc = (sec == 1) ? 0.125f : 1.0f;  // fold attention scale into q
#pragma unroll
    for (int nt = 0; nt < 4; ++nt) {
      const int n = bn * 128 + wn * 64 + nt * 16 + lc;
      const float bias = b1[n];
#pragma unroll
      for (int mt = 0; mt < 4; ++mt) {
        const int m0 = bm * 128 + wm * 64 + mt * 16 + quad * 4;
#pragma unroll
        for (int r = 0; r < 4; ++r)
          h[(size_t)(m0 + r) * 2048 + n] = f2bf(silu_f(acc[mt][nt][r] + bias) * osc);
      }
    }
  }
}

// ---------------- k2: causal silu-attention (Q-tile 64, K-tile 128) ----------------
// Sc^T = K·Q^T so C-regs are t-consecutive -> b64 packed writes to Ps[q][t]
__global__ __launch_bounds__(256, 3) void attn_kernel(
    const unsigned short* __restrict__ h,   // q @ +512 (pre-scaled), k @ +1024
    const unsigned short* __restrict__ vt,  // [32][64][2048]
    float* __restrict__ o)                  // [8192][512] = [b][s][hh*64+d]
{
  __shared__ __align__(16) unsigned short Ks[16 * 528];  // [16 grp][8 t][64 d]; Q staging first
  __shared__ __align__(16) unsigned short Vs[16 * 528];  // [16 grp][4 d][128 t]
  __shared__ __align__(16) unsigned short Ps[64 * 136];  // [64 q][136 t]
  const int tid = threadIdx.x;
  const int w = tid >> 6, l = tid & 63;
  const int bh = blockIdx.x & 31;
  const int qi = 31 - (blockIdx.x >> 5);  // LPT: longest blocks dispatch first
  const int b = bh >> 3, hh = bh & 7;
  const int quad = l >> 4, lc = l & 15;
  const int r8 = l >> 3, c8 = l & 7;
  const int wm = w & 1, wn = w >> 1;
  const int q0 = qi * 64;
  const int nk = (qi >> 1) + 1;
  const int klanebase = (lc >> 3) * 528 + (lc & 7) * 64 + quad * 8;

  // stage Q [64 q][64 d] into Ks area
  {
    const unsigned short* qg =
        h + (size_t)(b * 2048 + q0 + w * 16 + r8) * 2048 + 512 + hh * 64 + c8 * 8;
#pragma unroll
    for (int i = 0; i < 2; ++i)
      gl_lds16(qg + (size_t)i * 8 * 2048, Ks + (w * 16 + i * 8) * 64);
  }
  __syncthreads();
  short8 qf[2][2];
#pragma unroll
  for (int nt = 0; nt < 2; ++nt)
#pragma unroll
    for (int kk = 0; kk < 2; ++kk)
      qf[nt][kk] = *(const short8*)(Ks + (wn * 32 + nt * 16 + lc) * 64 + kk * 32 + quad * 8);

  f32x4 oacc[4] = {};

  const unsigned short* kg =
      h + (size_t)(b * 2048 + w * 32 + r8) * 2048 + 1024 + hh * 64 + c8 * 8;
  const unsigned short* vg = vt + (size_t)(bh * 64 + w * 16 + quad) * 2048 + lc * 8;

  for (int ti = 0; ti < nk; ++ti) {
    __syncthreads();  // prev readers of Ks/Vs/Ps done (iter0: qf loads done)
    const int toff = ti * 128;
#pragma unroll
    for (int i = 0; i < 4; ++i) {
      gl_lds16(kg + (size_t)(toff + i * 8) * 2048, Ks + (w * 4 + i) * 528);
      gl_lds16(vg + (size_t)(i * 4) * 2048 + toff, Vs + (w * 4 + i) * 528);
    }
    __syncthreads();

    // Sc^T = K Q^T : wave covers t[wm*64..+64) x q[wn*32..+32)
    f32x4 sc[4][2] = {};
#pragma unroll
    for (int kk = 0; kk < 2; ++kk) {
      short8 kf[4];
#pragma unroll
      for (int mt = 0; mt < 4; ++mt)
        kf[mt] = *(const short8*)(Ks + (wm * 8 + mt * 2) * 528 + klanebase + kk * 32);
#pragma unroll
      for (int mt = 0; mt < 4; ++mt)
#pragma unroll
        for (int nt = 0; nt < 2; ++nt)
          sc[mt][nt] = __builtin_amdgcn_mfma_f32_16x16x32_bf16(kf[mt], qf[nt][kk], sc[mt][nt], 0, 0, 0);
    }

    // silu (+causal mask on last tile) -> packed b64 writes Ps[q][t]
    if (ti < nk - 1) {
#pragma unroll
      for (int mt = 0; mt < 4; ++mt) {
        const int tloc = wm * 64 + mt * 16 + quad * 4;
#pragma unroll
        for (int nt = 0; nt < 2; ++nt) {
          const int qloc = wn * 32 + nt * 16 + lc;
          ushort4 pk;
          pk.x = f2bf(silu_f(sc[mt][nt][0]));
          pk.y = f2bf(silu_f(sc[mt][nt][1]));
          pk.z = f2bf(silu_f(sc[mt][nt][2]));
          pk.w = f2bf(silu_f(sc[mt][nt][3]));
          *(ushort4*)(Ps + qloc * 136 + tloc) = pk;
        }
      }
    } else {
#pragma unroll
      for (int mt = 0; mt < 4; ++mt) {
        const int tloc = wm * 64 + mt * 16 + quad * 4;
        const int tg = toff + tloc;
#pragma unroll
        for (int nt = 0; nt < 2; ++nt) {
          const int qloc = wn * 32 + nt * 16 + lc;
          const int qg = q0 + qloc;
          ushort4 pk;
          pk.x = (tg + 0 <= qg) ? f2bf(silu_f(sc[mt][nt][0])) : (unsigned short)0;
          pk.y = (tg + 1 <= qg) ? f2bf(silu_f(sc[mt][nt][1])) : (unsigned short)0;
          pk.z = (tg + 2 <= qg) ? f2bf(silu_f(sc[mt][nt][2])) : (unsigned short)0;
          pk.w = (tg + 3 <= qg) ? f2bf(silu_f(sc[mt][nt][3])) : (unsigned short)0;
          *(ushort4*)(Ps + qloc * 136 + tloc) = pk;
        }
      }
    }
    __syncthreads();

    // O += P V : wave covers q[w*16..+16) x d[0..64)
#pragma unroll
    for (int ks = 0; ks < 4; ++ks) {
      short8 pf = *(const short8*)(Ps + (w * 16 + lc) * 136 + ks * 32 + quad * 8);
#pragma unroll
      for (int nt = 0; nt < 4; ++nt) {
        short8 vf = *(const short8*)(Vs + (nt * 4 + (lc >> 2)) * 528 + (lc & 3) * 128 +
                                     ks * 32 + quad * 8);
        oacc[nt] = __builtin_amdgcn_mfma_f32_16x16x32_bf16(pf, vf, oacc[nt], 0, 0, 0);
      }
    }
  }

  float* og = o + (size_t)(b * 2048 + q0 + w * 16) * 512 + hh * 64;
#pragma unroll
  for (int nt = 0; nt < 4; ++nt)
#pragma unroll
    for (int r = 0; r < 4; ++r)
      og[(quad * 4 + r) * 512 + nt * 16 + lc] = oacc[nt][r];
}

// ---------------- k3: layernorm * gate -> y (bf16) ----------------
__global__ __launch_bounds__(256) void ln_gate_kernel(
    const float* __restrict__ o, const unsigned short* __restrict__ h,
    const float* __restrict__ lng, const float* __restrict__ lnb,
    unsigned short* __restrict__ y) {
  const int row = blockIdx.x * 4 + (threadIdx.x >> 6);
  const int l = threadIdx.x & 63;
  const float4* orow = (const float4*)(o + (size_t)row * 512);
  float4 a = orow[l * 2], c = orow[l * 2 + 1];
  float s0 = a.x + a.y + a.z + a.w + c.x + c.y + c.z + c.w;
#pragma unroll
  for (int off = 32; off > 0; off >>= 1) s0 += __shfl_xor(s0, off);
  const float mean = s0 * (1.0f / 512.0f);
  float dx[8] = {a.x - mean, a.y - mean, a.z - mean, a.w - mean,
                 c.x - mean, c.y - mean, c.z - mean, c.w - mean};
  float sq = 0.f;
#pragma unroll
  for (int j = 0; j < 8; ++j) sq += dx[j] * dx[j];
#pragma unroll
  for (int off = 32; off > 0; off >>= 1) sq += __shfl_xor(sq, off);
  const float inv = rsqrtf(sq * (1.0f / 512.0f) + 1e-5f);
  const float4* g4 = (const float4*)lng;
  const float4* b4 = (const float4*)lnb;
  float4 g0 = g4[l * 2], g1 = g4[l * 2 + 1], bb0 = b4[l * 2], bb1 = b4[l * 2 + 1];
  const unsigned short* grow = h + (size_t)row * 2048;  // gate = cols [0,512)
  ushort4 gr0 = *(const ushort4*)(grow + l * 8);
  ushort4 gr1 = *(const ushort4*)(grow + l * 8 + 4);
  float gg[8] = {g0.x, g0.y, g0.z, g0.w, g1.x, g1.y, g1.z, g1.w};
  float bbv[8] = {bb0.x, bb0.y, bb0.z, bb0.w, bb1.x, bb1.y, bb1.z, bb1.w};
  float gv[8] = {bf2f(gr0.x), bf2f(gr0.y), bf2f(gr0.z), bf2f(gr0.w),
                 bf2f(gr1.x), bf2f(gr1.y), bf2f(gr1.z), bf2f(gr1.w)};
  ushort4 p0, p1;
  p0.x = f2bf((dx[0] * inv * gg[0] + bbv[0]) * gv[0]);
  p0.y = f2bf((dx[1] * inv * gg[1] + bbv[1]) * gv[1]);
  p0.z = f2bf((dx[2] * inv * gg[2] + bbv[2]) * gv[2]);
  p0.w = f2bf((dx[3] * inv * gg[3] + bbv[3]) * gv[3]);
  p1.x = f2bf((dx[4] * inv * gg[4] + bbv[4]) * gv[4]);
  p1.y = f2bf((dx[5] * inv * gg[5] + bbv[5]) * gv[5]);
  p1.z = f2bf((dx[6] * inv * gg[6] + bbv[6]) * gv[6]);
  p1.w = f2bf((dx[7] * inv * gg[7] + bbv[7]) * gv[7]);
  ushort4* yrow = (ushort4*)(y + (size_t)row * 512);
  yrow[l * 2] = p0;
  yrow[l * 2 + 1] = p1;
}

// ---------------- k4: GEMM2 + bias -> out (fp32) ----------------
__global__ __launch_bounds__(256, 2) void gemm2_kernel(
    const unsigned short* __restrict__ yb,   // [8192][512]
    const unsigned short* __restrict__ w2b,  // [512][512]
    const float* __restrict__ b2, float* __restrict__ out) {
  __shared__ __align__(16) unsigned short As[16 * 528];
  __shared__ __align__(16) unsigned short Bs[16 * 528];
  const int tid = threadIdx.x;
  const int w = tid >> 6, l = tid & 63;
  const int bm = blockIdx.x & 63, bn = blockIdx.x >> 6;
  const int wm = w & 1, wn = w >> 1;
  const int quad = l >> 4, lc = l & 15;
  const int r8 = l >> 3, c8 = l & 7;
  const int lanebase = (lc >> 3) * 528 + (lc & 7) * 64 + quad * 8;

  f32x4 acc[4][4] = {};
  const unsigned short* ga = yb + (size_t)(bm * 128 + w * 32 + r8) * 512 + c8 * 8;
  const unsigned short* gb = w2b + (size_t)(bn * 128 + w * 32 + r8) * 512 + c8 * 8;

  for (int kt = 0; kt < 512; kt += 64) {
#pragma unroll
    for (int i = 0; i < 4; ++i) {
      gl_lds16(ga + i * 8 * 512 + kt, As + (w * 4 + i) * 528);
      gl_lds16(gb + i * 8 * 512 + kt, Bs + (w * 4 + i) * 528);
    }
    __syncthreads();
#pragma unroll
    for (int kk = 0; kk < 2; ++kk) {
      short8 af[4], bf[4];
#pragma unroll
      for (int mt = 0; mt < 4; ++mt)
        af[mt] = *(const short8*)(As + (wm * 8 + mt * 2) * 528 + lanebase + kk * 32);
#pragma unroll
      for (int nt = 0; nt < 4; ++nt)
        bf[nt] = *(const short8*)(Bs + (wn * 8 + nt * 2) * 528 + lanebase + kk * 32);
#pragma unroll
      for (int mt = 0; mt < 4; ++mt)
#pragma unroll
        for (int nt = 0; nt < 4; ++nt)
          acc[mt][nt] = __builtin_amdgcn_mfma_f32_16x16x32_bf16(af[mt], bf[nt], acc[mt][nt], 0, 0, 0);
    }
    __syncthreads();
  }

#pragma unroll
  for (int nt = 0; nt < 4; ++nt) {
    const int n = bn * 128 + wn * 64 + nt * 16 + lc;
    const float bias = b2[n];
#pragma unroll
    for (int mt = 0; mt < 4; ++mt) {
      const int m0 = bm * 128 + wm * 64 + mt * 16 + quad * 4;
#pragma unroll
      for (int r = 0; r < 4; ++r)
        out[(size_t)(m0 + r) * 512 + n] = acc[mt][nt][r] + bias;
    }
  }
}

extern "C" void kernel_launch(void* const* d_in, const int* in_sizes, int n_in,
                              void* d_out, int out_size, void* d_ws, size_t ws_size,
                              hipStream_t stream) {
  const float* x = (const float*)d_in[0];
  const float* W1 = (const float*)d_in[1];
  const float* b1 = (const float*)d_in[2];
  const float* lng = (const float*)d_in[3];
  const float* lnb = (const float*)d_in[4];
  const float* W2 = (const float*)d_in[5];
  const float* b2 = (const float*)d_in[6];
  float* out = (float*)d_out;
  char* ws = (char*)d_ws;

  unsigned short* xb  = (unsigned short*)(ws);
  unsigned short* w1b = (unsigned short*)(ws + 8388608);
  unsigned short* w2b = (unsigned short*)(ws + 10485760);
  unsigned short* h   = (unsigned short*)(ws + 11010048);
  unsigned short* vt  = (unsigned short*)(ws + 44564480);
  float* o            = (float*)(ws + 52953088);
  unsigned short* yb  = (unsigned short*)(ws + 69730304);

  convert_kernel<<<5376, 256, 0, stream>>>(x, W1, W2, xb, w1b, w2b);
  gemm1_kernel<<<1024, 256, 0, stream>>>(xb, w1b, b1, h, vt);
  attn_kernel<<<1024, 256, 0, stream>>>(h, vt, o);
  ln_gate_kernel<<<2048, 256, 0, stream>>>(o, h, lng, lnb, yb);
  gemm2_kernel<<<256, 256, 0, stream>>>(yb, w2b, b2, out);
}

// Round 3
// 158.913 us; speedup vs baseline: 1.3435x; 1.1481x over previous
//
#include <hip/hip_runtime.h>
#include <hip/hip_bf16.h>
#include <cstdint>

// HSTU fused block on MI355X.
//   k0: convert x,W1,W2 fp32->bf16
//   k1: h = silu(x@W1^T+b1) -> gate/q/k into h[8192][2048] (q pre-scaled 0.125), v -> Vt[b,h,d,t]
//       epilogue repacked through LDS -> 256B-coalesced stores
//   k2: causal silu-attention (Q-tile 64, K-tile 128, LPT), XOR-swizzled LDS
//   k3: y = (layernorm(o)*g+b) * gate  (bf16)
//   k4: out = y@W2^T + b2 (fp32)
// All MFMA staging tiles use XOR swizzle: LDS chunk c of row r holds global chunk c^(r&7)
// (gl_lds16 writes lane*16B at fixed LDS offset; we permute the *global* source per lane).

typedef __attribute__((ext_vector_type(8))) short short8;
typedef __attribute__((ext_vector_type(4))) float f32x4;

__device__ __forceinline__ unsigned short f2bf(float f) {
  union { float f; unsigned u; } v; v.f = f;
  unsigned r = v.u + 0x7FFFu + ((v.u >> 16) & 1u);
  return (unsigned short)(r >> 16);
}
__device__ __forceinline__ float bf2f(unsigned short h) {
  union { unsigned u; float f; } v; v.u = ((unsigned)h) << 16; return v.f;
}
__device__ __forceinline__ float fast_rcp(float x) {
#if __has_builtin(__builtin_amdgcn_rcpf)
  return __builtin_amdgcn_rcpf(x);
#else
  return 1.0f / x;
#endif
}
__device__ __forceinline__ float fast_exp2(float x) {
#if __has_builtin(__builtin_amdgcn_exp2f)
  return __builtin_amdgcn_exp2f(x);
#else
  return exp2f(x);
#endif
}
// silu without the IEEE-div sequence: x * rcp(1 + 2^(-x*log2e))
__device__ __forceinline__ float silu_f(float x) {
  return x * fast_rcp(1.0f + fast_exp2(-1.442695041f * x));
}
__device__ __forceinline__ unsigned pk2(float lo, float hi) {
  union { __hip_bfloat162 b; unsigned u; } cv;
  cv.b = __float22bfloat162_rn(make_float2(lo, hi));
  return cv.u;
}
__device__ __forceinline__ void gl_lds16(const void* g, void* l) {
  __builtin_amdgcn_global_load_lds(
      (const __attribute__((address_space(1))) void*)g,
      (__attribute__((address_space(3))) void*)l, 16, 0, 0);
}

// ---------------- k0: fp32 -> bf16 convert ----------------
__global__ void convert_kernel(const float* __restrict__ x, const float* __restrict__ w1,
                               const float* __restrict__ w2,
                               unsigned short* __restrict__ xb, unsigned short* __restrict__ w1b,
                               unsigned short* __restrict__ w2b) {
  int i = blockIdx.x * 256 + threadIdx.x;  // one float4 per thread
  const float* s; unsigned short* d;
  if (i < 1048576) { s = x; d = xb; }
  else if (i < 1048576 + 262144) { i -= 1048576; s = w1; d = w1b; }
  else { i -= (1048576 + 262144); if (i >= 65536) return; s = w2; d = w2b; }
  float4 f = ((const float4*)s)[i];
  uint2 o; o.x = pk2(f.x, f.y); o.y = pk2(f.z, f.w);
  ((uint2*)d)[i] = o;
}

// ---------------- k1: GEMM1 + bias + silu -> h (gate/q/k) and vt (v transposed) ----------------
__global__ __launch_bounds__(256, 2) void gemm1_kernel(
    const unsigned short* __restrict__ xb,   // [8192][512]
    const unsigned short* __restrict__ w1b,  // [2048][512]
    const float* __restrict__ b1,            // [2048]
    unsigned short* __restrict__ h,          // [8192][2048] (cols 1536+ unused)
    unsigned short* __restrict__ vt)         // [32*64][2048]  ((b*8+hh)*64+d, s)
{
  __shared__ __align__(16) unsigned short smem[16896];  // As|Bs (16384) then T[128][132]
  unsigned short* As = smem;          // [128][64] swizzled
  unsigned short* Bs = smem + 8192;
  const int tid = threadIdx.x;
  const int w = tid >> 6, l = tid & 63;
  const int bm = blockIdx.x & 63, bn = blockIdx.x >> 6;
  const int wm = w & 1, wn = w >> 1;
  const int quad = l >> 4, lc = l & 15, lc7 = lc & 7;
  const int r8 = l >> 3, c8 = (l & 7) ^ r8;  // swizzled global chunk

  f32x4 acc[4][4] = {};
  const unsigned short* ga = xb + (size_t)(bm * 128 + w * 32 + r8) * 512 + c8 * 8;
  const unsigned short* gb = w1b + (size_t)(bn * 128 + w * 32 + r8) * 512 + c8 * 8;

  for (int kt = 0; kt < 512; kt += 64) {
#pragma unroll
    for (int i = 0; i < 4; ++i) {
      gl_lds16(ga + i * 8 * 512 + kt, As + (w * 4 + i) * 512);
      gl_lds16(gb + i * 8 * 512 + kt, Bs + (w * 4 + i) * 512);
    }
    __syncthreads();
#pragma unroll
    for (int kk = 0; kk < 2; ++kk) {
      short8 af[4], bf[4];
#pragma unroll
      for (int mt = 0; mt < 4; ++mt)
        af[mt] = *(const short8*)(As + (wm * 64 + mt * 16 + lc) * 64 +
                                  (((kk * 4 + quad) ^ lc7) * 8));
#pragma unroll
      for (int nt = 0; nt < 4; ++nt)
        bf[nt] = *(const short8*)(Bs + (wn * 64 + nt * 16 + lc) * 64 +
                                  (((kk * 4 + quad) ^ lc7) * 8));
#pragma unroll
      for (int mt = 0; mt < 4; ++mt)
#pragma unroll
        for (int nt = 0; nt < 4; ++nt)
          acc[mt][nt] = __builtin_amdgcn_mfma_f32_16x16x32_bf16(af[mt], bf[nt], acc[mt][nt], 0, 0, 0);
    }
    __syncthreads();
  }

  // epilogue: repack C-tile through LDS T, then 256B-coalesced global stores
  unsigned short* T = smem;  // [128][132]
  const int sec = bn >> 2;   // 0 gate, 1 q, 2 k, 3 v (uniform per block)
  if (sec == 3) {
    // T[d_local][s_local]: regs hold 4 consecutive s at fixed n=d -> b64 LDS writes
#pragma unroll
    for (int nt = 0; nt < 4; ++nt) {
      const int nl = wn * 64 + nt * 16 + lc;
      const float bias = b1[bn * 128 + nl];
#pragma unroll
      for (int mt = 0; mt < 4; ++mt) {
        const int sl = wm * 64 + mt * 16 + quad * 4;
        uint2 pk;
        pk.x = pk2(silu_f(acc[mt][nt][0] + bias), silu_f(acc[mt][nt][1] + bias));
        pk.y = pk2(silu_f(acc[mt][nt][2] + bias), silu_f(acc[mt][nt][3] + bias));
        *(uint2*)(T + nl * 132 + sl) = pk;
      }
    }
  } else {
    const float osc = (sec == 1) ? 0.125f : 1.0f;  // fold attention scale into q
#pragma unroll
    for (int nt = 0; nt < 4; ++nt) {
      const int nl = wn * 64 + nt * 16 + lc;
      const float bias = b1[bn * 128 + nl];
#pragma unroll
      for (int mt = 0; mt < 4; ++mt) {
        const int sl = wm * 64 + mt * 16 + quad * 4;
#pragma unroll
        for (int r = 0; r < 4; ++r)
          T[(sl + r) * 132 + nl] = f2bf(silu_f(acc[mt][nt][r] + bias) * osc);
      }
    }
  }
  __syncthreads();
  const int rrow = tid >> 4, rcol = (tid & 15) * 8;
  if (sec == 3) {
    const int bq = bm >> 4, sbase = (bm & 15) * 128;
#pragma unroll
    for (int p = 0; p < 8; ++p) {
      const int row = p * 16 + rrow;
      const int n = bn * 128 + row, hh = (n >> 6) & 7, d = n & 63;
      *(short8*)(vt + (size_t)((bq * 8 + hh) * 64 + d) * 2048 + sbase + rcol) =
          *(const short8*)(T + row * 132 + rcol);
    }
  } else {
#pragma unroll
    for (int p = 0; p < 8; ++p) {
      const int row = p * 16 + rrow;
      *(short8*)(h + (size_t)(bm * 128 + row) * 2048 + bn * 128 + rcol) =
          *(const short8*)(T + row * 132 + rcol);
    }
  }
}

// ---------------- k2: causal silu-attention (Q-tile 64, K-tile 128) ----------------
__global__ __launch_bounds__(256, 3) void attn_kernel(
    const unsigned short* __restrict__ h,   // q @ +512 (pre-scaled), k @ +1024
    const unsigned short* __restrict__ vt,  // [32*64][2048]
    float* __restrict__ o)                  // [8192][512]
{
  __shared__ __align__(16) unsigned short Ks[128 * 64];  // swizzled; Q staged here first
  __shared__ __align__(16) unsigned short Vs[64 * 128];  // [d][t] swizzled
  __shared__ __align__(16) unsigned short Ps[64 * 136];  // [q][t] pad
  const int tid = threadIdx.x;
  const int w = tid >> 6, l = tid & 63;
  const int bh = blockIdx.x & 31;
  const int qi = 31 - (blockIdx.x >> 5);  // LPT: longest first
  const int b = bh >> 3, hh = bh & 7;
  const int quad = l >> 4, lc = l & 15, lc7 = lc & 7;
  const int r8 = l >> 3, c8 = (l & 7) ^ r8;
  const int wm = w & 1, wn = w >> 1;
  const int q0 = qi * 64;
  const int nk = (qi >> 1) + 1;

  // stage Q [64][64] into Ks area (swizzled)
  {
    const unsigned short* qg =
        h + (size_t)(b * 2048 + q0 + w * 16 + r8) * 2048 + 512 + hh * 64 + c8 * 8;
#pragma unroll
    for (int i = 0; i < 2; ++i)
      gl_lds16(qg + (size_t)i * 8 * 2048, Ks + (w * 2 + i) * 512);
  }
  __syncthreads();
  short8 qf[2][2];
#pragma unroll
  for (int nt = 0; nt < 2; ++nt)
#pragma unroll
    for (int kk = 0; kk < 2; ++kk)
      qf[nt][kk] = *(const short8*)(Ks + (wn * 32 + nt * 16 + lc) * 64 +
                                    (((kk * 4 + quad) ^ lc7) * 8));

  f32x4 oacc[4] = {};

  const unsigned short* kg =
      h + (size_t)(b * 2048 + w * 32 + r8) * 2048 + 1024 + hh * 64 + c8 * 8;
  const int vrow = l >> 4, vcol = l & 15;
  const unsigned short* vgE =
      vt + (size_t)(bh * 64 + w * 16 + vrow) * 2048 + ((vcol ^ vrow) * 8);
  const unsigned short* vgO =
      vt + (size_t)(bh * 64 + w * 16 + vrow) * 2048 + ((vcol ^ vrow ^ 4) * 8);

  for (int ti = 0; ti < nk; ++ti) {
    __syncthreads();  // prev readers done
    const int toff = ti * 128;
#pragma unroll
    for (int i = 0; i < 4; ++i) {
      gl_lds16(kg + (size_t)(toff + i * 8) * 2048, Ks + (w * 4 + i) * 512);
      const unsigned short* vsrc = ((i & 1) ? vgO : vgE) + (size_t)(i * 4) * 2048 + toff;
      gl_lds16(vsrc, Vs + (w * 4 + i) * 512);
    }
    __syncthreads();

    // Sc^T = K Q^T : wave covers t[wm*64..+64) x q[wn*32..+32)
    f32x4 sc[4][2] = {};
#pragma unroll
    for (int kk = 0; kk < 2; ++kk) {
      short8 kf[4];
#pragma unroll
      for (int mt = 0; mt < 4; ++mt)
        kf[mt] = *(const short8*)(Ks + (wm * 64 + mt * 16 + lc) * 64 +
                                  (((kk * 4 + quad) ^ lc7) * 8));
#pragma unroll
      for (int mt = 0; mt < 4; ++mt)
#pragma unroll
        for (int nt = 0; nt < 2; ++nt)
          sc[mt][nt] = __builtin_amdgcn_mfma_f32_16x16x32_bf16(kf[mt], qf[nt][kk], sc[mt][nt], 0, 0, 0);
    }

    // silu (+causal mask on last tile) -> packed b64 writes Ps[q][t]
    if (ti < nk - 1) {
#pragma unroll
      for (int mt = 0; mt < 4; ++mt) {
        const int tloc = wm * 64 + mt * 16 + quad * 4;
#pragma unroll
        for (int nt = 0; nt < 2; ++nt) {
          const int qloc = wn * 32 + nt * 16 + lc;
          uint2 pk;
          pk.x = pk2(silu_f(sc[mt][nt][0]), silu_f(sc[mt][nt][1]));
          pk.y = pk2(silu_f(sc[mt][nt][2]), silu_f(sc[mt][nt][3]));
          *(uint2*)(Ps + qloc * 136 + tloc) = pk;
        }
      }
    } else {
#pragma unroll
      for (int mt = 0; mt < 4; ++mt) {
        const int tloc = wm * 64 + mt * 16 + quad * 4;
        const int tg = toff + tloc;
#pragma unroll
        for (int nt = 0; nt < 2; ++nt) {
          const int qloc = wn * 32 + nt * 16 + lc;
          const int qg = q0 + qloc;
          float v0 = (tg + 0 <= qg) ? silu_f(sc[mt][nt][0]) : 0.0f;
          float v1 = (tg + 1 <= qg) ? silu_f(sc[mt][nt][1]) : 0.0f;
          float v2 = (tg + 2 <= qg) ? silu_f(sc[mt][nt][2]) : 0.0f;
          float v3 = (tg + 3 <= qg) ? silu_f(sc[mt][nt][3]) : 0.0f;
          uint2 pk; pk.x = pk2(v0, v1); pk.y = pk2(v2, v3);
          *(uint2*)(Ps + qloc * 136 + tloc) = pk;
        }
      }
    }
    __syncthreads();

    // O += P V : wave covers q[w*16..+16) x d[0..64)
#pragma unroll
    for (int ks = 0; ks < 4; ++ks) {
      short8 pf = *(const short8*)(Ps + (w * 16 + lc) * 136 + ks * 32 + quad * 8);
#pragma unroll
      for (int nt = 0; nt < 4; ++nt) {
        short8 vf = *(const short8*)(Vs + (nt * 16 + lc) * 128 +
                                     (((ks * 4 + quad) ^ lc7) * 8));
        oacc[nt] = __builtin_amdgcn_mfma_f32_16x16x32_bf16(pf, vf, oacc[nt], 0, 0, 0);
      }
    }
  }

  float* og = o + (size_t)(b * 2048 + q0 + w * 16) * 512 + hh * 64;
#pragma unroll
  for (int nt = 0; nt < 4; ++nt)
#pragma unroll
    for (int r = 0; r < 4; ++r)
      og[(quad * 4 + r) * 512 + nt * 16 + lc] = oacc[nt][r];
}

// ---------------- k3: layernorm * gate -> y (bf16) ----------------
__global__ __launch_bounds__(256) void ln_gate_kernel(
    const float* __restrict__ o, const unsigned short* __restrict__ h,
    const float* __restrict__ lng, const float* __restrict__ lnb,
    unsigned short* __restrict__ y) {
  const int row = blockIdx.x * 4 + (threadIdx.x >> 6);
  const int l = threadIdx.x & 63;
  const float4* orow = (const float4*)(o + (size_t)row * 512);
  float4 a = orow[l * 2], c = orow[l * 2 + 1];
  float s0 = a.x + a.y + a.z + a.w + c.x + c.y + c.z + c.w;
#pragma unroll
  for (int off = 32; off > 0; off >>= 1) s0 += __shfl_xor(s0, off);
  const float mean = s0 * (1.0f / 512.0f);
  float dx[8] = {a.x - mean, a.y - mean, a.z - mean, a.w - mean,
                 c.x - mean, c.y - mean, c.z - mean, c.w - mean};
  float sq = 0.f;
#pragma unroll
  for (int j = 0; j < 8; ++j) sq += dx[j] * dx[j];
#pragma unroll
  for (int off = 32; off > 0; off >>= 1) sq += __shfl_xor(sq, off);
  const float inv = rsqrtf(sq * (1.0f / 512.0f) + 1e-5f);
  const float4* g4 = (const float4*)lng;
  const float4* b4 = (const float4*)lnb;
  float4 g0 = g4[l * 2], g1 = g4[l * 2 + 1], bb0 = b4[l * 2], bb1 = b4[l * 2 + 1];
  const unsigned short* grow = h + (size_t)row * 2048;  // gate = cols [0,512)
  ushort4 gr0 = *(const ushort4*)(grow + l * 8);
  ushort4 gr1 = *(const ushort4*)(grow + l * 8 + 4);
  float gg[8] = {g0.x, g0.y, g0.z, g0.w, g1.x, g1.y, g1.z, g1.w};
  float bbv[8] = {bb0.x, bb0.y, bb0.z, bb0.w, bb1.x, bb1.y, bb1.z, bb1.w};
  float gv[8] = {bf2f(gr0.x), bf2f(gr0.y), bf2f(gr0.z), bf2f(gr0.w),
                 bf2f(gr1.x), bf2f(gr1.y), bf2f(gr1.z), bf2f(gr1.w)};
  float r[8];
#pragma unroll
  for (int j = 0; j < 8; ++j) r[j] = (dx[j] * inv * gg[j] + bbv[j]) * gv[j];
  uint2 p0, p1;
  p0.x = pk2(r[0], r[1]); p0.y = pk2(r[2], r[3]);
  p1.x = pk2(r[4], r[5]); p1.y = pk2(r[6], r[7]);
  uint2* yrow = (uint2*)(y + (size_t)row * 512);
  yrow[l * 2] = p0;
  yrow[l * 2 + 1] = p1;
}

// ---------------- k4: GEMM2 + bias -> out (fp32) ----------------
__global__ __launch_bounds__(256, 2) void gemm2_kernel(
    const unsigned short* __restrict__ yb,   // [8192][512]
    const unsigned short* __restrict__ w2b,  // [512][512]
    const float* __restrict__ b2, float* __restrict__ out) {
  __shared__ __align__(16) unsigned short As[128 * 64];
  __shared__ __align__(16) unsigned short Bs[128 * 64];
  const int tid = threadIdx.x;
  const int w = tid >> 6, l = tid & 63;
  const int bm = blockIdx.x & 63, bn = blockIdx.x >> 6;
  const int wm = w & 1, wn = w >> 1;
  const int quad = l >> 4, lc = l & 15, lc7 = lc & 7;
  const int r8 = l >> 3, c8 = (l & 7) ^ r8;

  f32x4 acc[4][4] = {};
  const unsigned short* ga = yb + (size_t)(bm * 128 + w * 32 + r8) * 512 + c8 * 8;
  const unsigned short* gb = w2b + (size_t)(bn * 128 + w * 32 + r8) * 512 + c8 * 8;

  for (int kt = 0; kt < 512; kt += 64) {
#pragma unroll
    for (int i = 0; i < 4; ++i) {
      gl_lds16(ga + i * 8 * 512 + kt, As + (w * 4 + i) * 512);
      gl_lds16(gb + i * 8 * 512 + kt, Bs + (w * 4 + i) * 512);
    }
    __syncthreads();
#pragma unroll
    for (int kk = 0; kk < 2; ++kk) {
      short8 af[4], bf[4];
#pragma unroll
      for (int mt = 0; mt < 4; ++mt)
        af[mt] = *(const short8*)(As + (wm * 64 + mt * 16 + lc) * 64 +
                                  (((kk * 4 + quad) ^ lc7) * 8));
#pragma unroll
      for (int nt = 0; nt < 4; ++nt)
        bf[nt] = *(const short8*)(Bs + (wn * 64 + nt * 16 + lc) * 64 +
                                  (((kk * 4 + quad) ^ lc7) * 8));
#pragma unroll
      for (int mt = 0; mt < 4; ++mt)
#pragma unroll
        for (int nt = 0; nt < 4; ++nt)
          acc[mt][nt] = __builtin_amdgcn_mfma_f32_16x16x32_bf16(af[mt], bf[nt], acc[mt][nt], 0, 0, 0);
    }
    __syncthreads();
  }

#pragma unroll
  for (int nt = 0; nt < 4; ++nt) {
    const int n = bn * 128 + wn * 64 + nt * 16 + lc;
    const float bias = b2[n];
#pragma unroll
    for (int mt = 0; mt < 4; ++mt) {
      const int m0 = bm * 128 + wm * 64 + mt * 16 + quad * 4;
#pragma unroll
      for (int r = 0; r < 4; ++r)
        out[(size_t)(m0 + r) * 512 + n] = acc[mt][nt][r] + bias;
    }
  }
}

extern "C" void kernel_launch(void* const* d_in, const int* in_sizes, int n_in,
                              void* d_out, int out_size, void* d_ws, size_t ws_size,
                              hipStream_t stream) {
  const float* x = (const float*)d_in[0];
  const float* W1 = (const float*)d_in[1];
  const float* b1 = (const float*)d_in[2];
  const float* lng = (const float*)d_in[3];
  const float* lnb = (const float*)d_in[4];
  const float* W2 = (const float*)d_in[5];
  const float* b2 = (const float*)d_in[6];
  float* out = (float*)d_out;
  char* ws = (char*)d_ws;

  unsigned short* xb  = (unsigned short*)(ws);
  unsigned short* w1b = (unsigned short*)(ws + 8388608);
  unsigned short* w2b = (unsigned short*)(ws + 10485760);
  unsigned short* h   = (unsigned short*)(ws + 11010048);
  unsigned short* vt  = (unsigned short*)(ws + 44564480);
  float* o            = (float*)(ws + 52953088);
  unsigned short* yb  = (unsigned short*)(ws + 69730304);

  convert_kernel<<<5376, 256, 0, stream>>>(x, W1, W2, xb, w1b, w2b);
  gemm1_kernel<<<1024, 256, 0, stream>>>(xb, w1b, b1, h, vt);
  attn_kernel<<<1024, 256, 0, stream>>>(h, vt, o);
  ln_gate_kernel<<<2048, 256, 0, stream>>>(o, h, lng, lnb, yb);
  gemm2_kernel<<<256, 256, 0, stream>>>(yb, w2b, b2, out);
}